// Round 1
// baseline (596.549 us; speedup 1.0000x reference)
//
#include <hip/hip_runtime.h>
#include <hip/hip_bf16.h>

namespace {

constexpr int BB  = 8;      // batch
constexpr int CC  = 256;    // channels
constexpr int NN  = 4096;   // H*W tokens
constexpr int NG  = 16;     // groups
constexpr int CPG = CC / NG;
constexpr float EPS_GN = 1e-6f;
constexpr float EPS_L2 = 1e-12f;

// ---------------- GroupNorm stats: one block per (b,g) ----------------
__global__ __launch_bounds__(256) void gn_stats_k(const float* __restrict__ x,
                                                  float* __restrict__ stats) {
  int bg = blockIdx.x;  // 0..127 ; group data is contiguous: bg*CPG*NN
  const float4* base = (const float4*)(x + (size_t)bg * CPG * NN);
  float s = 0.f, ss = 0.f;
  for (int i = threadIdx.x; i < CPG * NN / 4; i += 256) {
    float4 v = base[i];
    s  += v.x + v.y + v.z + v.w;
    ss += v.x * v.x + v.y * v.y + v.z * v.z + v.w * v.w;
  }
#pragma unroll
  for (int off = 32; off; off >>= 1) {
    s  += __shfl_down(s, off);
    ss += __shfl_down(ss, off);
  }
  __shared__ float sh[8];
  int lane = threadIdx.x & 63, wid = threadIdx.x >> 6;
  if (lane == 0) { sh[wid] = s; sh[wid + 4] = ss; }
  __syncthreads();
  if (threadIdx.x == 0) {
    float S  = sh[0] + sh[1] + sh[2] + sh[3];
    float SS = sh[4] + sh[5] + sh[6] + sh[7];
    const float inv = 1.f / (float)(CPG * NN);
    float mean = S * inv;
    float var  = SS * inv - mean * mean;
    stats[bg * 2 + 0] = mean;
    stats[bg * 2 + 1] = rsqrtf(var + EPS_GN);
  }
}

// ---------------- GroupNorm apply (vectorized) ----------------
__global__ __launch_bounds__(256) void gn_apply_k(const float* __restrict__ x,
                                                  const float* __restrict__ stats,
                                                  const float* __restrict__ gamma,
                                                  const float* __restrict__ beta,
                                                  float* __restrict__ gnx) {
  size_t i = (size_t)blockIdx.x * 256 + threadIdx.x;  // quad index; grid covers exactly
  size_t e = i * 4;
  int c  = (int)((e >> 12) & (CC - 1));   // NN = 2^12
  int bg = (int)(e >> 20) * NG + (c >> 4);  // CC*NN = 2^20, CPG=16
  float mean = stats[bg * 2 + 0], rstd = stats[bg * 2 + 1];
  float ga = gamma[c] * rstd;
  float be = beta[c] - mean * ga;
  float4 v = ((const float4*)x)[i];
  float4 o;
  o.x = v.x * ga + be; o.y = v.y * ga + be;
  o.z = v.z * ga + be; o.w = v.w * ga + be;
  ((float4*)gnx)[i] = o;
}

// ---------------- Generic NN GEMM: Y[b] = W[b] (MxK) @ X[b] (KxN) ----------------
// 64x64 tile, 256 threads, 4x4 per thread. Optional bias[m] and residual add.
template <bool BIAS, bool RESID>
__global__ __launch_bounds__(256) void gemm64_k(const float* __restrict__ W, long wstride,
                                                const float* __restrict__ X, long xstride,
                                                const float* __restrict__ bias,
                                                const float* __restrict__ resid,
                                                float* __restrict__ Y, long ystride,
                                                int M, int K, int N) {
  __shared__ float As[16][68];  // [k][m], padded
  __shared__ float Bs[16][64];  // [k][n]
  const int b = blockIdx.z;
  const float* Wb = W + (size_t)b * wstride;
  const float* Xb = X + (size_t)b * xstride;
  const int m0 = blockIdx.y * 64, n0 = blockIdx.x * 64;
  const int tid = threadIdx.x;
  const int tx = tid & 15, ty = tid >> 4;
  const int arow = tid >> 2, acol = (tid & 3) * 4;
  const int brow = tid >> 4, bcol = (tid & 15) * 4;
  float acc[4][4] = {};
  for (int k0 = 0; k0 < K; k0 += 16) {
    float4 av = *(const float4*)(Wb + (size_t)(m0 + arow) * K + k0 + acol);
    float4 bv = *(const float4*)(Xb + (size_t)(k0 + brow) * N + n0 + bcol);
    __syncthreads();
    As[acol + 0][arow] = av.x; As[acol + 1][arow] = av.y;
    As[acol + 2][arow] = av.z; As[acol + 3][arow] = av.w;
    *(float4*)&Bs[brow][bcol] = bv;
    __syncthreads();
#pragma unroll
    for (int k = 0; k < 16; ++k) {
      float4 a4 = *(const float4*)&As[k][ty * 4];
      float4 b4 = *(const float4*)&Bs[k][tx * 4];
      float a[4] = {a4.x, a4.y, a4.z, a4.w};
      float bb[4] = {b4.x, b4.y, b4.z, b4.w};
#pragma unroll
      for (int i = 0; i < 4; ++i)
#pragma unroll
        for (int j = 0; j < 4; ++j) acc[i][j] += a[i] * bb[j];
    }
  }
#pragma unroll
  for (int i = 0; i < 4; ++i) {
    int m = m0 + ty * 4 + i;
    float bv_ = BIAS ? bias[m] : 0.f;
#pragma unroll
    for (int j = 0; j < 4; ++j) {
      int n = n0 + tx * 4 + j;
      float v = acc[i][j] + bv_;
      if (RESID) v += resid[(size_t)b * ystride + (size_t)m * N + n];
      Y[(size_t)b * ystride + (size_t)m * N + n] = v;
    }
  }
}

// ---------------- L2 scales: 1/max(||row||,eps) over N for Q and K rows ----------------
__global__ __launch_bounds__(256) void l2scale_k(const float* __restrict__ qkv,
                                                 float* __restrict__ scales) {
  int row = blockIdx.x;  // 0..4095 : b*512 + r, r<256 -> Q row r, r>=256 -> K row r
  int b = row >> 9;
  int r = row & 511;
  const float4* p = (const float4*)(qkv + ((size_t)b * 3 * CC + r) * NN);
  float ss = 0.f;
  for (int i = threadIdx.x; i < NN / 4; i += 256) {
    float4 v = p[i];
    ss += v.x * v.x + v.y * v.y + v.z * v.z + v.w * v.w;
  }
#pragma unroll
  for (int off = 32; off; off >>= 1) ss += __shfl_down(ss, off);
  __shared__ float sh[4];
  int lane = threadIdx.x & 63, wid = threadIdx.x >> 6;
  if (lane == 0) sh[wid] = ss;
  __syncthreads();
  if (threadIdx.x == 0) {
    float S = sh[0] + sh[1] + sh[2] + sh[3];
    scales[row] = 1.f / fmaxf(sqrtf(S), EPS_L2);
  }
}

// ---------------- Attention logits: A[b,c,d] = temp*qs*ks * sum_n Q[c,n]K[d,n] ----------------
__global__ __launch_bounds__(256) void attn_nt_k(const float* __restrict__ qkv,
                                                 const float* __restrict__ scales,
                                                 const float* __restrict__ temp,
                                                 float* __restrict__ attn) {
  __shared__ float Qs[64][36];
  __shared__ float Ks[64][36];
  const int b = blockIdx.z;
  const float* Qb = qkv + (size_t)b * 3 * CC * NN;
  const float* Kb = Qb + (size_t)CC * NN;
  const int c0 = blockIdx.y * 64, d0 = blockIdx.x * 64;
  const int tid = threadIdx.x;
  const int tx = tid & 15, ty = tid >> 4;
  float acc[4][4] = {};
  for (int n0 = 0; n0 < NN; n0 += 32) {
    __syncthreads();
#pragma unroll
    for (int t = 0; t < 2; ++t) {
      int s = tid + t * 256;       // 0..511
      int row = s >> 3;            // 0..63
      int col = (s & 7) * 4;       // 0..28
      float4 qv = *(const float4*)(Qb + (size_t)(c0 + row) * NN + n0 + col);
      float4 kv = *(const float4*)(Kb + (size_t)(d0 + row) * NN + n0 + col);
      *(float4*)&Qs[row][col] = qv;
      *(float4*)&Ks[row][col] = kv;
    }
    __syncthreads();
#pragma unroll
    for (int k = 0; k < 32; k += 4) {
      float4 qa[4], kb[4];
#pragma unroll
      for (int i = 0; i < 4; ++i) qa[i] = *(const float4*)&Qs[ty * 4 + i][k];
#pragma unroll
      for (int j = 0; j < 4; ++j) kb[j] = *(const float4*)&Ks[tx * 4 + j][k];
#pragma unroll
      for (int i = 0; i < 4; ++i)
#pragma unroll
        for (int j = 0; j < 4; ++j)
          acc[i][j] += qa[i].x * kb[j].x + qa[i].y * kb[j].y +
                       qa[i].z * kb[j].z + qa[i].w * kb[j].w;
    }
  }
  float T = temp[0];
#pragma unroll
  for (int i = 0; i < 4; ++i) {
    int c = c0 + ty * 4 + i;
    float qs = scales[b * 512 + c];
#pragma unroll
    for (int j = 0; j < 4; ++j) {
      int d = d0 + tx * 4 + j;
      float ks = scales[b * 512 + 256 + d];
      attn[((size_t)b * CC + c) * CC + d] = acc[i][j] * qs * ks * T;
    }
  }
}

// ---------------- Row softmax over 256 (one block per row) ----------------
__global__ __launch_bounds__(256) void softmax_k(float* __restrict__ attn) {
  float* p = attn + (size_t)blockIdx.x * CC;
  int t = threadIdx.x;
  float v = p[t];
  float m = v;
#pragma unroll
  for (int off = 32; off; off >>= 1) m = fmaxf(m, __shfl_xor(m, off));
  __shared__ float sm[4], ssum[4];
  int lane = t & 63, wid = t >> 6;
  if (lane == 0) sm[wid] = m;
  __syncthreads();
  m = fmaxf(fmaxf(sm[0], sm[1]), fmaxf(sm[2], sm[3]));
  float e = expf(v - m);
  float s = e;
#pragma unroll
  for (int off = 32; off; off >>= 1) s += __shfl_xor(s, off);
  if (lane == 0) ssum[wid] = s;
  __syncthreads();
  s = ssum[0] + ssum[1] + ssum[2] + ssum[3];
  p[t] = e / s;
}

}  // namespace

extern "C" void kernel_launch(void* const* d_in, const int* in_sizes, int n_in,
                              void* d_out, int out_size, void* d_ws, size_t ws_size,
                              hipStream_t stream) {
  const float* x      = (const float*)d_in[0];
  const float* gamma  = (const float*)d_in[1];
  const float* beta   = (const float*)d_in[2];
  const float* qkv_w  = (const float*)d_in[3];
  const float* qkv_b  = (const float*)d_in[4];
  const float* temp   = (const float*)d_in[5];
  const float* proj_w = (const float*)d_in[6];
  const float* proj_b = (const float*)d_in[7];
  float* out = (float*)d_out;

  char* ws = (char*)d_ws;
  float* stats  = (float*)(ws);                     // 128*2*4      = 1 KB
  float* scales = (float*)(ws + 1024);              // 4096*4       = 16 KB
  float* attn   = (float*)(ws + 32768);             // 8*256*256*4  = 2 MB
  float* gnx    = (float*)(ws + (size_t)(4u << 20));            // 33.5 MB (reused as attnout)
  float* qkv    = (float*)(ws + (size_t)(4u << 20) + 33554432u);// 100.7 MB
  const size_t required = (size_t)(4u << 20) + 33554432u + 100663296u;
  if (ws_size < required) return;  // workspace too small: bail (visible as wrong output)

  // 1. GroupNorm
  gn_stats_k<<<128, 256, 0, stream>>>(x, stats);
  gn_apply_k<<<(BB * CC * NN / 4) / 256, 256, 0, stream>>>(x, stats, gamma, beta, gnx);

  // 2. QKV projection: qkv[b] (768x4096) = qkv_w (768x256) @ gnx[b] (256x4096) + qkv_b
  gemm64_k<true, false><<<dim3(NN / 64, 768 / 64, BB), 256, 0, stream>>>(
      qkv_w, 0, gnx, (long)CC * NN, qkv_b, nullptr, qkv, (long)3 * CC * NN, 768, CC, NN);

  // 3. L2 scales for Q and K rows
  l2scale_k<<<BB * 512, 256, 0, stream>>>(qkv, scales);

  // 4. Attention logits (scaled) + 5. softmax
  attn_nt_k<<<dim3(CC / 64, CC / 64, BB), 256, 0, stream>>>(qkv, scales, temp, attn);
  softmax_k<<<BB * CC, 256, 0, stream>>>(attn);

  // 6. PV: attnout[b] (256x4096) = attn[b] (256x256) @ V[b] (256x4096)  (into gnx buffer)
  gemm64_k<false, false><<<dim3(NN / 64, CC / 64, BB), 256, 0, stream>>>(
      attn, (long)CC * CC, qkv + (size_t)2 * CC * NN, (long)3 * CC * NN,
      nullptr, nullptr, gnx, (long)CC * NN, CC, CC, NN);

  // 7. proj + bias + residual -> out
  gemm64_k<true, true><<<dim3(NN / 64, CC / 64, BB), 256, 0, stream>>>(
      proj_w, 0, gnx, (long)CC * NN, proj_b, x, out, (long)CC * NN, CC, CC, NN);
}

// Round 2
// 208.337 us; speedup vs baseline: 2.8634x; 2.8634x over previous
//
#include <hip/hip_runtime.h>
#include <hip/hip_bf16.h>

namespace {

constexpr int BB  = 8;
constexpr int CC  = 256;
constexpr int NN  = 4096;
constexpr int CPG = 16;
constexpr float EPS_GN = 1e-6f;
constexpr float EPS_L2 = 1e-12f;

typedef __attribute__((ext_vector_type(8))) short bf16x8;
typedef __attribute__((ext_vector_type(4))) float f32x4;
typedef __attribute__((ext_vector_type(4))) unsigned short u16x4;

__device__ __forceinline__ unsigned short f2bf(float f) {
  union { __hip_bfloat16 h; unsigned short u; } cv;
  cv.h = __float2bfloat16(f);
  return cv.u;
}

// ---------------- weight f32 -> bf16 ----------------
__global__ __launch_bounds__(256) void cvt_bf_k(const float* __restrict__ src,
                                                unsigned short* __restrict__ dst, int n4) {
  int i = blockIdx.x * 256 + threadIdx.x;
  if (i < n4) {
    float4 v = ((const float4*)src)[i];
    u16x4 o;
    o.x = f2bf(v.x); o.y = f2bf(v.y); o.z = f2bf(v.z); o.w = f2bf(v.w);
    ((u16x4*)dst)[i] = o;
  }
}

// ---------------- GroupNorm stats: one block per (b,g) ----------------
__global__ __launch_bounds__(256) void gn_stats_k(const float* __restrict__ x,
                                                  float* __restrict__ stats) {
  int bg = blockIdx.x;
  const float4* base = (const float4*)(x + (size_t)bg * CPG * NN);
  float s = 0.f, ss = 0.f;
  for (int i = threadIdx.x; i < CPG * NN / 4; i += 256) {
    float4 v = base[i];
    s  += v.x + v.y + v.z + v.w;
    ss += v.x * v.x + v.y * v.y + v.z * v.z + v.w * v.w;
  }
#pragma unroll
  for (int off = 32; off; off >>= 1) {
    s  += __shfl_down(s, off);
    ss += __shfl_down(ss, off);
  }
  __shared__ float sh[8];
  int lane = threadIdx.x & 63, wid = threadIdx.x >> 6;
  if (lane == 0) { sh[wid] = s; sh[wid + 4] = ss; }
  __syncthreads();
  if (threadIdx.x == 0) {
    float S  = sh[0] + sh[1] + sh[2] + sh[3];
    float SS = sh[4] + sh[5] + sh[6] + sh[7];
    const float inv = 1.f / (float)(CPG * NN);
    float mean = S * inv;
    float var  = SS * inv - mean * mean;
    stats[bg * 2 + 0] = mean;
    stats[bg * 2 + 1] = rsqrtf(var + EPS_GN);
  }
}

// ---------------- GroupNorm apply + transpose: x (b,c,n) f32 -> gnxT (b,n,c) bf16 ----------------
__global__ __launch_bounds__(256) void gn_apply_t_k(const float* __restrict__ x,
                                                    const float* __restrict__ stats,
                                                    const float* __restrict__ gamma,
                                                    const float* __restrict__ beta,
                                                    unsigned short* __restrict__ gnxT) {
  __shared__ float tile[64][65];
  const int b = blockIdx.z, c0 = blockIdx.y * 64, n0 = blockIdx.x * 64;
  const int t = threadIdx.x;
  const float* xb = x + ((size_t)b << 20);
  const int cr = t >> 4, n4 = (t & 15) * 4;
#pragma unroll
  for (int p = 0; p < 4; ++p) {
    int c = cr + p * 16;
    float4 v = *(const float4*)(xb + (size_t)(c0 + c) * NN + n0 + n4);
    tile[c][n4 + 0] = v.x; tile[c][n4 + 1] = v.y;
    tile[c][n4 + 2] = v.z; tile[c][n4 + 3] = v.w;
  }
  __syncthreads();
  const int nr = t >> 4, c4 = (t & 15) * 4;
#pragma unroll
  for (int p = 0; p < 4; ++p) {
    int n = nr + p * 16;
    u16x4 pk;
#pragma unroll
    for (int k = 0; k < 4; ++k) {
      int c = c0 + c4 + k;
      int bg = b * 16 + (c >> 4);
      float ga = gamma[c] * stats[bg * 2 + 1];
      float be = beta[c] - stats[bg * 2 + 0] * ga;
      float v = tile[c4 + k][n] * ga + be;
      if (k == 0) pk.x = f2bf(v);
      else if (k == 1) pk.y = f2bf(v);
      else if (k == 2) pk.z = f2bf(v);
      else pk.w = f2bf(v);
    }
    *(u16x4*)(gnxT + ((size_t)b * NN + n0 + n) * CC + c0 + c4) = pk;
  }
}

// ---------------- L2 scales from bf16 Q/K rows ----------------
__global__ __launch_bounds__(256) void l2scale_bf_k(const unsigned short* __restrict__ qk,
                                                    float* __restrict__ scales) {
  const int row = blockIdx.x;  // b*512 + r (qk is [b][512][4096] contiguous)
  const int4* p = (const int4*)(qk + ((size_t)row << 12));
  float ss = 0.f;
  for (int i = threadIdx.x; i < 512; i += 256) {
    int4 v = p[i];
#pragma unroll
    for (int j2 = 0; j2 < 4; ++j2) {
      unsigned wv = (j2 == 0) ? (unsigned)v.x : (j2 == 1) ? (unsigned)v.y
                   : (j2 == 2) ? (unsigned)v.z : (unsigned)v.w;
      float f0 = __uint_as_float(wv << 16);
      float f1 = __uint_as_float(wv & 0xffff0000u);
      ss += f0 * f0 + f1 * f1;
    }
  }
#pragma unroll
  for (int off = 32; off; off >>= 1) ss += __shfl_down(ss, off);
  __shared__ float sh[4];
  int lane = threadIdx.x & 63, wid = threadIdx.x >> 6;
  if (lane == 0) sh[wid] = ss;
  __syncthreads();
  if (threadIdx.x == 0)
    scales[row] = 1.f / fmaxf(sqrtf(sh[0] + sh[1] + sh[2] + sh[3]), EPS_L2);
}

// ---------------- MFMA NT-GEMM: C[m][n] = sum_k A[m][k] * B[n][k] ----------------
// 128x128 tile, BK=64, 256 threads (4 waves, 2x2), 4x4 fragments of 16x16x32.
// MODE 0: QKV   (bias; m<512 -> bf16 [m][n] to outU0; m>=512 -> bf16 transposed [n][m-512] to outU1)
// MODE 1: attn  (split-K partials, f32 [slice][m][n] to outF)
// MODE 2: PV    (bf16 transposed [n][m] to outU1)
// MODE 3: proj  (bias + residual, f32 [m][n] to outF)
template <int MODE>
__global__ __launch_bounds__(256) void mfma_nt_k(
    const unsigned short* __restrict__ A, long abst, int lda,
    const unsigned short* __restrict__ B, long bbst, int ldb,
    int K, int KS,
    const float* __restrict__ bias, const float* __restrict__ resid,
    float* __restrict__ outF, unsigned short* __restrict__ outU0,
    unsigned short* __restrict__ outU1) {
  __shared__ unsigned short As[128 * 64];
  __shared__ unsigned short Bs[128 * 64];
  const int z = blockIdx.z;
  const int b = z / KS, sl = z % KS;
  const int kper = K / KS;
  const unsigned short* Ab = A + (size_t)b * abst;
  const unsigned short* Bb = B + (size_t)b * bbst;
  const int m0 = blockIdx.y * 128, n0 = blockIdx.x * 128;
  const int tid = threadIdx.x;
  const int l = tid & 63, w = tid >> 6;
  const int wm = w >> 1, wn = w & 1;

  // staging: thread t loads 64B (4 x 16B chunks) of one row-half; XOR-swizzled LDS slot
  const int sr = tid >> 1;
  const int sb = (tid & 1) * 4;
  const unsigned short* aG = Ab + (size_t)(m0 + sr) * lda + (size_t)sl * kper + sb * 8;
  const unsigned short* bG = Bb + (size_t)(n0 + sr) * ldb + (size_t)sl * kper + sb * 8;
  int wOff[4];
#pragma unroll
  for (int c = 0; c < 4; ++c)
    wOff[c] = sr * 128 + (((sb + c) ^ (sr & 7)) << 4);

  // fragment read offsets (kk=0); kk=1 differs by XOR 0x40 (slot bit 2)
  int rdA[4], rdB[4];
#pragma unroll
  for (int i = 0; i < 4; ++i) {
    int rm = wm * 64 + i * 16 + (l & 15);
    rdA[i] = rm * 128 + ((((l >> 4)) ^ (l & 7)) << 4);
    int rn = wn * 64 + i * 16 + (l & 15);
    rdB[i] = rn * 128 + ((((l >> 4)) ^ (l & 7)) << 4);
  }

  f32x4 zero = {0.f, 0.f, 0.f, 0.f};
  f32x4 acc[4][4];
#pragma unroll
  for (int i = 0; i < 4; ++i)
#pragma unroll
    for (int j = 0; j < 4; ++j) acc[i][j] = zero;

  const int ksteps = kper / 64;
  for (int ks = 0; ks < ksteps; ++ks) {
    int4 av[4], bv[4];
#pragma unroll
    for (int c = 0; c < 4; ++c) {
      av[c] = *(const int4*)(aG + c * 8);
      bv[c] = *(const int4*)(bG + c * 8);
    }
    aG += 64; bG += 64;
    __syncthreads();
#pragma unroll
    for (int c = 0; c < 4; ++c) {
      *(int4*)((char*)As + wOff[c]) = av[c];
      *(int4*)((char*)Bs + wOff[c]) = bv[c];
    }
    __syncthreads();
#pragma unroll
    for (int kk = 0; kk < 2; ++kk) {
      bf16x8 af[4], bfr[4];
#pragma unroll
      for (int i = 0; i < 4; ++i) {
        af[i]  = *(const bf16x8*)((const char*)As + (rdA[i] ^ (kk << 6)));
        bfr[i] = *(const bf16x8*)((const char*)Bs + (rdB[i] ^ (kk << 6)));
      }
#pragma unroll
      for (int i = 0; i < 4; ++i)
#pragma unroll
        for (int j = 0; j < 4; ++j)
          acc[i][j] = __builtin_amdgcn_mfma_f32_16x16x32_bf16(af[i], bfr[j], acc[i][j], 0, 0, 0);
    }
  }

  // D layout per 16x16 frag: col = l&15, row = (l>>4)*4 + r   [guide §3, m89/m91]
  const int mB = m0 + wm * 64 + ((l >> 4) << 2);
  const int nB = n0 + wn * 64 + (l & 15);

  if (MODE == 0) {
    if (m0 < 512) {  // Q/K region: bf16 [b][m][n], row stride 4096
#pragma unroll
      for (int i = 0; i < 4; ++i) {
        int mI = mB + i * 16;
#pragma unroll
        for (int r = 0; r < 4; ++r) {
          float bv_ = bias[mI + r];
          size_t rowo = (size_t)b * (512 * 4096) + (size_t)(mI + r) * 4096;
#pragma unroll
          for (int j = 0; j < 4; ++j)
            outU0[rowo + nB + j * 16] = f2bf(acc[i][j][r] + bv_);
        }
      }
    } else {  // V region: bf16 transposed [b][n][m-512]
#pragma unroll
      for (int i = 0; i < 4; ++i) {
        int mI = mB + i * 16;
        float b0 = bias[mI], b1 = bias[mI + 1], b2 = bias[mI + 2], b3 = bias[mI + 3];
#pragma unroll
        for (int j = 0; j < 4; ++j) {
          u16x4 pk;
          pk.x = f2bf(acc[i][j][0] + b0);
          pk.y = f2bf(acc[i][j][1] + b1);
          pk.z = f2bf(acc[i][j][2] + b2);
          pk.w = f2bf(acc[i][j][3] + b3);
          *(u16x4*)(outU1 + ((size_t)b * 4096 + nB + j * 16) * 256 + (mI - 512)) = pk;
        }
      }
    }
  } else if (MODE == 1) {
    float* po = outF + (size_t)(b * KS + sl) * 65536;
#pragma unroll
    for (int i = 0; i < 4; ++i)
#pragma unroll
      for (int r = 0; r < 4; ++r)
#pragma unroll
        for (int j = 0; j < 4; ++j)
          po[(size_t)(mB + i * 16 + r) * 256 + nB + j * 16] = acc[i][j][r];
  } else if (MODE == 2) {
#pragma unroll
    for (int i = 0; i < 4; ++i) {
      int mI = mB + i * 16;
#pragma unroll
      for (int j = 0; j < 4; ++j) {
        u16x4 pk;
        pk.x = f2bf(acc[i][j][0]); pk.y = f2bf(acc[i][j][1]);
        pk.z = f2bf(acc[i][j][2]); pk.w = f2bf(acc[i][j][3]);
        *(u16x4*)(outU1 + ((size_t)b * 4096 + nB + j * 16) * 256 + mI) = pk;
      }
    }
  } else {  // MODE 3
#pragma unroll
    for (int i = 0; i < 4; ++i) {
      int mI = mB + i * 16;
#pragma unroll
      for (int r = 0; r < 4; ++r) {
        float bv_ = bias[mI + r];
        size_t rowo = ((size_t)b << 20) + (size_t)(mI + r) * 4096;
#pragma unroll
        for (int j = 0; j < 4; ++j)
          outF[rowo + nB + j * 16] = acc[i][j][r] + bv_ + resid[rowo + nB + j * 16];
      }
    }
  }
}

// ---------------- reduce split-K partials + scale + softmax -> bf16 attn ----------------
__global__ __launch_bounds__(256) void attn_fix_k(const float* __restrict__ part,
                                                  const float* __restrict__ scales,
                                                  const float* __restrict__ temp,
                                                  unsigned short* __restrict__ attn_bf) {
  const int bc = blockIdx.x;  // b*256 + c
  const int b = bc >> 8, c = bc & 255;
  const int d = threadIdx.x;
  float v = 0.f;
#pragma unroll
  for (int s = 0; s < 8; ++s)
    v += part[((size_t)(b * 8 + s) << 16) + (c << 8) + d];
  v *= scales[b * 512 + c] * scales[b * 512 + 256 + d] * temp[0];
  float mx = v;
#pragma unroll
  for (int off = 32; off; off >>= 1) mx = fmaxf(mx, __shfl_xor(mx, off));
  __shared__ float sm[4], ssum[4];
  int lane = d & 63, wid = d >> 6;
  if (lane == 0) sm[wid] = mx;
  __syncthreads();
  mx = fmaxf(fmaxf(sm[0], sm[1]), fmaxf(sm[2], sm[3]));
  float e = expf(v - mx);
  float s = e;
#pragma unroll
  for (int off = 32; off; off >>= 1) s += __shfl_xor(s, off);
  if (lane == 0) ssum[wid] = s;
  __syncthreads();
  s = ssum[0] + ssum[1] + ssum[2] + ssum[3];
  attn_bf[((size_t)bc << 8) + d] = f2bf(e / s);
}

}  // namespace

extern "C" void kernel_launch(void* const* d_in, const int* in_sizes, int n_in,
                              void* d_out, int out_size, void* d_ws, size_t ws_size,
                              hipStream_t stream) {
  const float* x      = (const float*)d_in[0];
  const float* gamma  = (const float*)d_in[1];
  const float* beta   = (const float*)d_in[2];
  const float* qkv_w  = (const float*)d_in[3];
  const float* qkv_b  = (const float*)d_in[4];
  const float* temp   = (const float*)d_in[5];
  const float* proj_w = (const float*)d_in[6];
  const float* proj_b = (const float*)d_in[7];
  float* out = (float*)d_out;

  char* ws = (char*)d_ws;
  const size_t MB = 1048576;
  unsigned short* qkv_w_bf = (unsigned short*)(ws);                 // 0.4 MB
  unsigned short* proj_w_bf = (unsigned short*)(ws + 512 * 1024);   // 0.13 MB
  float* stats   = (float*)(ws + 0xA0000);
  float* scales  = (float*)(ws + 0xA1000);
  unsigned short* attn_bf = (unsigned short*)(ws + 1 * MB);         // 1 MB
  float* part    = (float*)(ws + 2 * MB);                           // 16 MB
  unsigned short* gnxT = (unsigned short*)(ws + 18 * MB);           // 16.8 MB
  unsigned short* qk   = (unsigned short*)(ws + 35 * MB);           // 33.6 MB
  unsigned short* vT   = (unsigned short*)(ws + 69 * MB);           // 16.8 MB
  unsigned short* pvT  = (unsigned short*)(ws + 86 * MB);           // 16.8 MB
  if (ws_size < 103 * MB) return;

  // weights -> bf16
  cvt_bf_k<<<192, 256, 0, stream>>>(qkv_w, qkv_w_bf, 768 * 256 / 4);
  cvt_bf_k<<<64, 256, 0, stream>>>(proj_w, proj_w_bf, 256 * 256 / 4);

  // GroupNorm -> gnxT (b, n, c) bf16
  gn_stats_k<<<128, 256, 0, stream>>>(x, stats);
  gn_apply_t_k<<<dim3(64, 4, 8), 256, 0, stream>>>(x, stats, gamma, beta, gnxT);

  // QKV: [768x256] @ [4096x256]^T per batch; Q/K -> qk (c-major), V -> vT (token-major)
  mfma_nt_k<0><<<dim3(32, 6, 8), 256, 0, stream>>>(
      qkv_w_bf, 0, 256, gnxT, (long)NN * CC, 256, 256, 1,
      qkv_b, nullptr, nullptr, qk, vT);

  // L2 scales over Q/K rows
  l2scale_bf_k<<<4096, 256, 0, stream>>>(qk, scales);

  // attn logits: Q @ K^T over K=4096, split-K=8 -> f32 partials
  mfma_nt_k<1><<<dim3(2, 2, 64), 256, 0, stream>>>(
      qk, (long)512 * 4096, 4096, qk + (size_t)256 * 4096, (long)512 * 4096, 4096,
      4096, 8, nullptr, nullptr, part, nullptr, nullptr);

  // reduce + scale + softmax -> bf16 attn
  attn_fix_k<<<2048, 256, 0, stream>>>(part, scales, temp, attn_bf);

  // PV: attn [256x256] @ vT [4096x256]^T -> pvT (token-major bf16)
  mfma_nt_k<2><<<dim3(32, 2, 8), 256, 0, stream>>>(
      attn_bf, (long)CC * CC, 256, vT, (long)NN * CC, 256, 256, 1,
      nullptr, nullptr, nullptr, nullptr, pvT);

  // proj + bias + residual -> out (f32)
  mfma_nt_k<3><<<dim3(32, 2, 8), 256, 0, stream>>>(
      proj_w_bf, 0, 256, pvT, (long)NN * CC, 256, 256, 1,
      proj_b, x, out, nullptr, nullptr);
}